// Round 9
// baseline (847.871 us; speedup 1.0000x reference)
//
#include <hip/hip_runtime.h>
#include <stdint.h>

#define EMB 64
#define BN_EPS 1e-5f
#define BSH 8              // bucket = 256 consecutive dst nodes
#define CHUNK 4096         // edges per k_part block

__device__ __forceinline__ unsigned short f2b(float x) {
    unsigned u = __float_as_uint(x);
    u += 0x7FFFu + ((u >> 16) & 1u);   // round-to-nearest-even
    return (unsigned short)(u >> 16);
}
__device__ __forceinline__ float b2f(unsigned short v) {
    return __uint_as_float(((unsigned)v) << 16);
}

// ---------------- zero init (ws is poisoned 0xAA every call) ----------------
__global__ void k_zero(int* __restrict__ bcnt, float* __restrict__ stats,
                       int nb, int nstats) {
    int i = blockIdx.x * blockDim.x + threadIdx.x;
    if (i < nb) bcnt[i] = 0;
    if (i < nstats) stats[i] = 0.0f;
}

// ---------------- bucket histogram (dst read once, LDS-combined) ----------
__global__ void __launch_bounds__(256) k_bhist(const int* __restrict__ ei,
                                               int* __restrict__ bcnt,
                                               int E, int nb) {
    __shared__ int lh[256];
    const int tid = threadIdx.x;
    lh[tid] = 0;
    __syncthreads();
    int stride = gridDim.x * blockDim.x;
    for (int e = blockIdx.x * blockDim.x + tid; e < E; e += stride)
        atomicAdd(&lh[((unsigned)ei[E + e]) >> BSH], 1);
    __syncthreads();
    if (tid < nb && lh[tid]) atomicAdd(&bcnt[tid], lh[tid]);
}

// ---------------- single-block bucket scan ----------------
__global__ void __launch_bounds__(256) k_bscan(const int* __restrict__ bcnt,
                                               int* __restrict__ bbase,
                                               int* __restrict__ bcur, int nb) {
    __shared__ int a[256];
    const int t = threadIdx.x;
    int v = (t < nb) ? bcnt[t] : 0;
    a[t] = v;
    __syncthreads();
    for (int off = 1; off < 256; off <<= 1) {
        int x = (t >= off) ? a[t - off] : 0;
        __syncthreads();
        a[t] += x;
        __syncthreads();
    }
    int excl = a[t] - v;
    if (t < nb) { bbase[t] = excl; bcur[t] = excl; }
    if (t == nb - 1) bbase[nb] = a[t];
}

// ---------------- phase 1: compact edges into per-bucket runs --------------
__global__ void __launch_bounds__(256) k_part(
        const int* __restrict__ ei, const float* __restrict__ ew,
        int* __restrict__ bcur, int2* __restrict__ eG, int E) {
    __shared__ int lcnt[256], lbase[256], loff[256];
    const int tid = threadIdx.x;
    const int c0 = blockIdx.x * CHUNK;
    lcnt[tid] = 0;
    __syncthreads();
    int src[16], pk[16], g[16];
    float wt[16];
#pragma unroll
    for (int i = 0; i < 16; i++) {
        int e = c0 + i * 256 + tid;
        if (e < E) {
            int d = ei[E + e];
            src[i] = ei[e];
            wt[i] = ew[e];
            g[i] = ((unsigned)d) >> BSH;
            pk[i] = src[i] | ((d & 255) << 24);
            atomicAdd(&lcnt[g[i]], 1);
        } else g[i] = -1;
    }
    __syncthreads();
    if (lcnt[tid]) lbase[tid] = atomicAdd(&bcur[tid], lcnt[tid]);
    loff[tid] = 0;
    __syncthreads();
#pragma unroll
    for (int i = 0; i < 16; i++) {
        if (g[i] >= 0) {
            int pos = lbase[g[i]] + atomicAdd(&loff[g[i]], 1);
            eG[pos] = make_int2(pk[i], __float_as_int(wt[i]));
        }
    }
}

// ---------------- phase 2: exact CSR inside each bucket --------------------
__global__ void __launch_bounds__(256) k_build(
        const int2* __restrict__ eG, const int* __restrict__ bbase,
        int* __restrict__ rowst, int* __restrict__ counts,
        int2* __restrict__ pairs, int N) {
    __shared__ int lcnt[256], a[256], lcur[256];
    const int t = threadIdx.x;
    const int b = blockIdx.x;
    const int e0 = bbase[b], e1 = bbase[b + 1];
    lcnt[t] = 0;
    __syncthreads();
    for (int i = e0 + t; i < e1; i += 256)
        atomicAdd(&lcnt[((unsigned)eG[i].x) >> 24], 1);
    __syncthreads();
    int v = lcnt[t];
    a[t] = v;
    __syncthreads();
    for (int off = 1; off < 256; off <<= 1) {
        int x = (t >= off) ? a[t - off] : 0;
        __syncthreads();
        a[t] += x;
        __syncthreads();
    }
    int excl = a[t] - v;
    lcur[t] = excl;
    int node = (b << BSH) + t;
    if (node < N) { rowst[node] = e0 + excl; counts[node] = v; }
    __syncthreads();
    for (int i = e0 + t; i < e1; i += 256) {
        int2 p = eG[i];
        int loc = ((unsigned)p.x) >> 24;
        int pos = e0 + atomicAdd(&lcur[loc], 1);
        pairs[pos] = make_int2(p.x & 0x00FFFFFF, p.y);
    }
}

// ---------------- aggregation: wave-per-node, lane=feature, bf16 gathers ----
__global__ void k_agg(const unsigned short* __restrict__ hb,
                      const float* __restrict__ h,
                      const int* __restrict__ rowst,
                      const int* __restrict__ counts, const int2* __restrict__ pairs,
                      float* __restrict__ out, int N) {
    const int lane = threadIdx.x & 63;
    int wave = (blockIdx.x * blockDim.x + threadIdx.x) >> 6;
    const int nwaves = (gridDim.x * blockDim.x) >> 6;
    for (int node = wave; node < N; node += nwaves) {
        int un = __builtin_amdgcn_readfirstlane(node);
        int s = rowst[un];
        int end = s + counts[un];
        float a0 = 0.f, a1 = 0.f, a2 = 0.f, a3 = 0.f;
        float a4 = 0.f, a5 = 0.f, a6 = 0.f, a7 = 0.f;
        for (int e = s; e < end; e += 8) {
#define SLOT(K, ACC)                                                       \
            {                                                              \
                int idx = e + K;                                           \
                bool ok = idx < end;                                       \
                int2 p = pairs[ok ? idx : s];                              \
                float w = ok ? __int_as_float(p.y) : 0.f;                  \
                float vv = b2f(hb[(size_t)p.x * EMB + lane]);              \
                ACC = fmaf(w, vv, ACC);                                    \
            }
            SLOT(0, a0) SLOT(1, a1) SLOT(2, a2) SLOT(3, a3)
            SLOT(4, a4) SLOT(5, a5) SLOT(6, a6) SLOT(7, a7)
#undef SLOT
        }
        float self = h[(size_t)un * EMB + lane];
        out[(size_t)un * EMB + lane] =
            (((a0 + a1) + (a2 + a3)) + ((a4 + a5) + (a6 + a7))) + self;
    }
}

// ---------------- matmul, column-lane layout --------------------------------
// lane = output column j; W column j lives in 64 VGPRs (coalesced preload,
// L2-hot). A rows are wave-uniform -> s_load batches; FMAs use one SGPR
// operand each (v_fmac acc, s_a[f], v_w[f]). No LDS, no barriers. Stats
// reduced in registers per lane -> 2 global atomics per wave.
template <bool DO_STATS, bool B16OUT>
__global__ void __launch_bounds__(64) k_mmv(
        const float* __restrict__ in, const float* __restrict__ W,
        const float* __restrict__ bias,
        float* __restrict__ out, float* __restrict__ st_out,
        unsigned short* __restrict__ b16out, int N) {
    const int j = threadIdx.x;          // 0..63
    const int node0 = blockIdx.x * 32;
    const int nv = min(32, N - node0);

    float w[EMB];
#pragma unroll
    for (int f = 0; f < EMB; f++) w[f] = W[f * EMB + j];
    const float bj = bias[j];

    float s_sum = 0.f, s_sq = 0.f;
    for (int n = 0; n < nv; n++) {
        const float* ar = in + (size_t)(node0 + n) * EMB;   // uniform -> s_load
        float a0 = 0.f, a1 = 0.f, a2 = 0.f, a3 = 0.f;       // 4 indep chains
#pragma unroll
        for (int f = 0; f < EMB; f += 4) {
            a0 = fmaf(ar[f + 0], w[f + 0], a0);
            a1 = fmaf(ar[f + 1], w[f + 1], a1);
            a2 = fmaf(ar[f + 2], w[f + 2], a2);
            a3 = fmaf(ar[f + 3], w[f + 3], a3);
        }
        float acc = bj + ((a0 + a1) + (a2 + a3));
        if (DO_STATS) { s_sum += acc; s_sq = fmaf(acc, acc, s_sq); }
        out[(size_t)(node0 + n) * EMB + j] = acc;
        if (B16OUT) b16out[(size_t)(node0 + n) * EMB + j] = f2b(acc);
    }
    if (DO_STATS) {
        atomicAdd(&st_out[j], s_sum);
        atomicAdd(&st_out[EMB + j], s_sq);
    }
}

// ---------------- in-place BN + relu (between mm1 and mm2) ------------------
__global__ void k_bn1(float* __restrict__ t, const float* __restrict__ st,
                      const float* __restrict__ g, const float* __restrict__ be,
                      float invN, int total4) {
    int stride = gridDim.x * blockDim.x;
    for (int i4 = blockIdx.x * blockDim.x + threadIdx.x; i4 < total4; i4 += stride) {
        int c = i4 & 15;
        float4 uv = ((const float4*)t)[i4];
        float4 sv = ((const float4*)st)[c];
        float4 qv = ((const float4*)(st + EMB))[c];
        float4 gv = ((const float4*)g)[c];
        float4 bv = ((const float4*)be)[c];
        float4 o;
#define BN1(comp)                                                     \
        {                                                             \
            float m  = sv.comp * invN;                                \
            float va = fmaf(qv.comp, invN, -m * m);                   \
            float rs = rsqrtf(va + BN_EPS);                           \
            float sc = rs * gv.comp;                                  \
            float sh = fmaf(-m, sc, bv.comp);                         \
            o.comp = fmaxf(0.f, fmaf(uv.comp, sc, sh));               \
        }
        BN1(x) BN1(y) BN1(z) BN1(w)
#undef BN1
        ((float4*)t)[i4] = o;
    }
}

// ---------------- outer BN + relu + residual (+ bf16 copy) ----------------
__global__ void k_bnres(const float* __restrict__ u, const float* __restrict__ st,
                        const float* __restrict__ g, const float* __restrict__ be,
                        const float* __restrict__ hin, float* __restrict__ hout,
                        unsigned short* __restrict__ b16out,
                        float invN, int total4) {
    int stride = gridDim.x * blockDim.x;
    for (int i4 = blockIdx.x * blockDim.x + threadIdx.x; i4 < total4; i4 += stride) {
        int c = i4 & 15;
        float4 uv = ((const float4*)u)[i4];
        float4 hv = ((const float4*)hin)[i4];
        float4 sv = ((const float4*)st)[c];
        float4 qv = ((const float4*)(st + EMB))[c];
        float4 gv = ((const float4*)g)[c];
        float4 bv = ((const float4*)be)[c];
        float4 o;
#define BNR(comp)                                                     \
        {                                                             \
            float m  = sv.comp * invN;                                \
            float va = fmaf(qv.comp, invN, -m * m);                   \
            float rs = rsqrtf(va + BN_EPS);                           \
            float sc = rs * gv.comp;                                  \
            float sh = fmaf(-m, sc, bv.comp);                         \
            float r  = fmaxf(0.f, fmaf(uv.comp, sc, sh));             \
            o.comp = r + hv.comp;                                     \
        }
        BNR(x) BNR(y) BNR(z) BNR(w)
#undef BNR
        ((float4*)hout)[i4] = o;
        if (b16out) {
            ushort4 ob;
            ob.x = f2b(o.x); ob.y = f2b(o.y);
            ob.z = f2b(o.z); ob.w = f2b(o.w);
            ((ushort4*)b16out)[i4] = ob;
        }
    }
}

// ---------------- launcher ----------------
extern "C" void kernel_launch(void* const* d_in, const int* in_sizes, int n_in,
                              void* d_out, int out_size, void* d_ws, size_t ws_size,
                              hipStream_t stream) {
    const float* x     = (const float*)d_in[0];
    const int*   ei    = (const int*)d_in[1];
    const float* ew    = (const float*)d_in[3];
    const float* ae_w  = (const float*)d_in[4];
    const float* ae_b  = (const float*)d_in[5];
    const float* W1    = (const float*)d_in[6];
    const float* b1    = (const float*)d_in[7];
    const float* g1    = (const float*)d_in[8];
    const float* be1   = (const float*)d_in[9];
    const float* W2    = (const float*)d_in[10];
    const float* b2    = (const float*)d_in[11];
    const float* g_out = (const float*)d_in[12];
    const float* be_out= (const float*)d_in[13];

    const int N = in_sizes[0] / EMB;
    const int E = in_sizes[3];
    const int L = in_sizes[6] / (EMB * EMB);
    const float invN = 1.0f / (float)N;
    const int NBUCK = (N + 255) >> BSH;

    uintptr_t p = (uintptr_t)d_ws;
    auto alloc = [&](size_t bytes) -> void* {
        p = (p + 255) & ~(uintptr_t)255;
        void* r = (void*)p;
        p += bytes;
        return r;
    };
    float* h     = (float*)alloc((size_t)N * EMB * 4);
    float* bufa  = (float*)alloc((size_t)N * EMB * 4);
    float* buft  = (float*)alloc((size_t)N * EMB * 4);  // also hosts staged edges
    unsigned short* hb16 = (unsigned short*)alloc((size_t)N * EMB * 2);
    int*   counts= (int*)alloc((size_t)N * 4);
    int*   rowst = (int*)alloc((size_t)N * 4);
    int*   bcnt  = (int*)alloc(256 * 4);
    int*   bbase = (int*)alloc(257 * 4);
    int*   bcur  = (int*)alloc(256 * 4);
    int2*  pairs = (int2*)alloc((size_t)E * 8);
    float* stats = (float*)alloc((size_t)L * 2 * 2 * EMB * 4);
    int2*  eG    = (int2*)buft;
    (void)ws_size; (void)n_in; (void)out_size;

    const int nstats = L * 2 * 2 * EMB;
    int zgrid = ((NBUCK > nstats ? NBUCK : nstats) + 255) / 256;
    hipLaunchKernelGGL(k_zero, dim3(zgrid), dim3(256), 0, stream,
                       bcnt, stats, NBUCK, nstats);

    const int nt32 = (N + 31) / 32;
    // encoder: h = x @ ae_w + ae_b   (+ bf16 copy)
    hipLaunchKernelGGL((k_mmv<false, true>), dim3(nt32), dim3(64), 0, stream,
                       x, ae_w, ae_b, h, (float*)nullptr, hb16, N);

    // CSR build: bucket hist -> scan -> compact -> per-bucket exact CSR
    hipLaunchKernelGGL(k_bhist, dim3(120), dim3(256), 0, stream, ei, bcnt, E, NBUCK);
    hipLaunchKernelGGL(k_bscan, dim3(1), dim3(256), 0, stream, bcnt, bbase, bcur, NBUCK);
    hipLaunchKernelGGL(k_part, dim3((E + CHUNK - 1) / CHUNK), dim3(256), 0, stream,
                       ei, ew, bcur, eG, E);
    hipLaunchKernelGGL(k_build, dim3(NBUCK), dim3(256), 0, stream,
                       eG, bbase, rowst, counts, pairs, N);

    for (int l = 0; l < L; l++) {
        float* stats1 = stats + (size_t)(l * 2 + 0) * 2 * EMB;
        float* stats2 = stats + (size_t)(l * 2 + 1) * 2 * EMB;

        // agg + self  (bf16 gathers)
        hipLaunchKernelGGL(k_agg, dim3(2048), dim3(256), 0, stream,
                           hb16, h, rowst, counts, pairs, bufa, N);
        // t = agg @ W1 + b1   (+stats1)
        hipLaunchKernelGGL((k_mmv<true, false>), dim3(nt32), dim3(64), 0, stream,
                           bufa, W1 + (size_t)l * EMB * EMB, b1 + (size_t)l * EMB,
                           buft, stats1, (unsigned short*)nullptr, N);
        // t = relu(bn1(t))   (in place)
        hipLaunchKernelGGL(k_bn1, dim3(1024), dim3(256), 0, stream,
                           buft, stats1, g1 + (size_t)l * EMB, be1 + (size_t)l * EMB,
                           invN, N * 16);
        // u = t @ W2 + b2   (+stats2)
        hipLaunchKernelGGL((k_mmv<true, false>), dim3(nt32), dim3(64), 0, stream,
                           buft, W2 + (size_t)l * EMB * EMB, b2 + (size_t)l * EMB,
                           bufa, stats2, (unsigned short*)nullptr, N);
        // h = relu(bn2(u)) + h   (+ bf16 copy for next layer's gathers)
        float* hout = (l == L - 1) ? (float*)d_out : h;
        unsigned short* b16o = (l == L - 1) ? (unsigned short*)nullptr : hb16;
        hipLaunchKernelGGL(k_bnres, dim3(1024), dim3(256), 0, stream,
                           bufa, stats2, g_out + (size_t)l * EMB, be_out + (size_t)l * EMB,
                           h, hout, b16o, invN, N * 16);
    }
}

// Round 10
// 547.548 us; speedup vs baseline: 1.5485x; 1.5485x over previous
//
#include <hip/hip_runtime.h>
#include <stdint.h>

#define EMB 64
#define BN_EPS 1e-5f
#define BSH 8              // bucket = 256 consecutive dst nodes
#define CHUNK 4096         // edges per k_part block
#define TS 68              // LDS tile stride (floats): 2-way max bank aliasing

typedef short bfrag __attribute__((ext_vector_type(8)));   // 8 bf16 = 4 VGPRs
typedef float f32x4 __attribute__((ext_vector_type(4)));

__device__ __forceinline__ unsigned short f2b(float x) {
    unsigned u = __float_as_uint(x);
    u += 0x7FFFu + ((u >> 16) & 1u);   // round-to-nearest-even
    return (unsigned short)(u >> 16);
}
__device__ __forceinline__ float b2f(unsigned short v) {
    return __uint_as_float(((unsigned)v) << 16);
}

// ---------------- zero init (ws is poisoned 0xAA every call) ----------------
__global__ void k_zero(int* __restrict__ bcnt, float* __restrict__ stats,
                       int nb, int nstats) {
    int i = blockIdx.x * blockDim.x + threadIdx.x;
    if (i < nb) bcnt[i] = 0;
    if (i < nstats) stats[i] = 0.0f;
}

// ---------------- prep: weights -> transposed bf16; x -> bf16 --------------
__global__ void k_prep(const float* __restrict__ ae_w, const float* __restrict__ W1,
                       const float* __restrict__ W2, const float* __restrict__ x,
                       unsigned short* __restrict__ Wt16, unsigned short* __restrict__ x16,
                       int L, int N) {
    int gid = blockIdx.x * blockDim.x + threadIdx.x;
    const int nw = (1 + 2 * L) * EMB * EMB;
    if (gid < nw) {
        int m = gid >> 12;
        int j = (gid >> 6) & 63;   // output col
        int k = gid & 63;          // input feature
        const float* src = (m == 0) ? ae_w
                         : (m <= L ? W1 + (size_t)(m - 1) * EMB * EMB
                                   : W2 + (size_t)(m - 1 - L) * EMB * EMB);
        Wt16[gid] = f2b(src[k * EMB + j]);   // Wt[m][j][k] = W[k][j]
    } else {
        int i4 = gid - nw;
        if (i4 < N * 16) {
            float4 v = ((const float4*)x)[i4];
            ushort4 o;
            o.x = f2b(v.x); o.y = f2b(v.y); o.z = f2b(v.z); o.w = f2b(v.w);
            ((ushort4*)x16)[i4] = o;
        }
    }
}

// ---------------- bucket histogram (dst read once, LDS-combined) ----------
__global__ void __launch_bounds__(256) k_bhist(const int* __restrict__ ei,
                                               int* __restrict__ bcnt,
                                               int E, int nb) {
    __shared__ int lh[256];
    const int tid = threadIdx.x;
    lh[tid] = 0;
    __syncthreads();
    int stride = gridDim.x * blockDim.x;
    for (int e = blockIdx.x * blockDim.x + tid; e < E; e += stride)
        atomicAdd(&lh[((unsigned)ei[E + e]) >> BSH], 1);
    __syncthreads();
    if (tid < nb && lh[tid]) atomicAdd(&bcnt[tid], lh[tid]);
}

// ---------------- single-block bucket scan ----------------
__global__ void __launch_bounds__(256) k_bscan(const int* __restrict__ bcnt,
                                               int* __restrict__ bbase,
                                               int* __restrict__ bcur, int nb) {
    __shared__ int a[256];
    const int t = threadIdx.x;
    int v = (t < nb) ? bcnt[t] : 0;
    a[t] = v;
    __syncthreads();
    for (int off = 1; off < 256; off <<= 1) {
        int x = (t >= off) ? a[t - off] : 0;
        __syncthreads();
        a[t] += x;
        __syncthreads();
    }
    int excl = a[t] - v;
    if (t < nb) { bbase[t] = excl; bcur[t] = excl; }
    if (t == nb - 1) bbase[nb] = a[t];
}

// ---------------- phase 1: compact edges into per-bucket runs --------------
__global__ void __launch_bounds__(256) k_part(
        const int* __restrict__ ei, const float* __restrict__ ew,
        int* __restrict__ bcur, int2* __restrict__ eG, int E) {
    __shared__ int lcnt[256], lbase[256], loff[256];
    const int tid = threadIdx.x;
    const int c0 = blockIdx.x * CHUNK;
    lcnt[tid] = 0;
    __syncthreads();
    int src[16], pk[16], g[16];
    float wt[16];
#pragma unroll
    for (int i = 0; i < 16; i++) {
        int e = c0 + i * 256 + tid;
        if (e < E) {
            int d = ei[E + e];
            src[i] = ei[e];
            wt[i] = ew[e];
            g[i] = ((unsigned)d) >> BSH;
            pk[i] = src[i] | ((d & 255) << 24);
            atomicAdd(&lcnt[g[i]], 1);
        } else g[i] = -1;
    }
    __syncthreads();
    if (lcnt[tid]) lbase[tid] = atomicAdd(&bcur[tid], lcnt[tid]);
    loff[tid] = 0;
    __syncthreads();
#pragma unroll
    for (int i = 0; i < 16; i++) {
        if (g[i] >= 0) {
            int pos = lbase[g[i]] + atomicAdd(&loff[g[i]], 1);
            eG[pos] = make_int2(pk[i], __float_as_int(wt[i]));
        }
    }
}

// ---------------- phase 2: exact CSR inside each bucket --------------------
__global__ void __launch_bounds__(256) k_build(
        const int2* __restrict__ eG, const int* __restrict__ bbase,
        int* __restrict__ rowst, int* __restrict__ counts,
        int2* __restrict__ pairs, int N) {
    __shared__ int lcnt[256], a[256], lcur[256];
    const int t = threadIdx.x;
    const int b = blockIdx.x;
    const int e0 = bbase[b], e1 = bbase[b + 1];
    lcnt[t] = 0;
    __syncthreads();
    for (int i = e0 + t; i < e1; i += 256)
        atomicAdd(&lcnt[((unsigned)eG[i].x) >> 24], 1);
    __syncthreads();
    int v = lcnt[t];
    a[t] = v;
    __syncthreads();
    for (int off = 1; off < 256; off <<= 1) {
        int x = (t >= off) ? a[t - off] : 0;
        __syncthreads();
        a[t] += x;
        __syncthreads();
    }
    int excl = a[t] - v;
    lcur[t] = excl;
    int node = (b << BSH) + t;
    if (node < N) { rowst[node] = e0 + excl; counts[node] = v; }
    __syncthreads();
    for (int i = e0 + t; i < e1; i += 256) {
        int2 p = eG[i];
        int loc = ((unsigned)p.x) >> 24;
        int pos = e0 + atomicAdd(&lcur[loc], 1);
        pairs[pos] = make_int2(p.x & 0x00FFFFFF, p.y);
    }
}

// ---------------- aggregation: wave-per-node, bf16 in AND out --------------
__global__ void k_agg(const unsigned short* __restrict__ hb,
                      const float* __restrict__ h,
                      const int* __restrict__ rowst,
                      const int* __restrict__ counts, const int2* __restrict__ pairs,
                      unsigned short* __restrict__ out16, int N) {
    const int lane = threadIdx.x & 63;
    int wave = (blockIdx.x * blockDim.x + threadIdx.x) >> 6;
    const int nwaves = (gridDim.x * blockDim.x) >> 6;
    for (int node = wave; node < N; node += nwaves) {
        int un = __builtin_amdgcn_readfirstlane(node);
        int s = rowst[un];
        int end = s + counts[un];
        float a0 = 0.f, a1 = 0.f, a2 = 0.f, a3 = 0.f;
        float a4 = 0.f, a5 = 0.f, a6 = 0.f, a7 = 0.f;
        for (int e = s; e < end; e += 8) {
#define SLOT(K, ACC)                                                       \
            {                                                              \
                int idx = e + K;                                           \
                bool ok = idx < end;                                       \
                int2 p = pairs[ok ? idx : s];                              \
                float w = ok ? __int_as_float(p.y) : 0.f;                  \
                float vv = b2f(hb[(size_t)p.x * EMB + lane]);              \
                ACC = fmaf(w, vv, ACC);                                    \
            }
            SLOT(0, a0) SLOT(1, a1) SLOT(2, a2) SLOT(3, a3)
            SLOT(4, a4) SLOT(5, a5) SLOT(6, a6) SLOT(7, a7)
#undef SLOT
        }
        float self = h[(size_t)un * EMB + lane];
        float sum = (((a0 + a1) + (a2 + a3)) + ((a4 + a5) + (a6 + a7))) + self;
        out16[(size_t)un * EMB + lane] = f2b(sum);   // 128B/row, full-line
    }
}

// ---------------- MFMA matmul: block = 64-node tile, 4 waves ---------------
// Wave wv: rows [wv*16,+16) x all 64 cols; 4 col-tiles x 2 K-steps of
// v_mfma_f32_16x16x32_bf16, fp32 accumulate. A[m=lane&15][k=quad*8+j],
// C col=lane&15,row=quad*4+reg (verified layouts). Epilogue via stride-68
// LDS tile -> coalesced flush + stats (+ optional bf16 pack).
template <bool DO_STATS, bool B16OUT>
__global__ void __launch_bounds__(256) k_mmx(
        const unsigned short* __restrict__ in16, const unsigned short* __restrict__ Wt,
        const float* __restrict__ bias,
        float* __restrict__ out, float* __restrict__ st_out,
        unsigned short* __restrict__ b16out, int N) {
    __shared__ float tb[64 * TS];
    __shared__ float st_part[128];
    const int tid = threadIdx.x;
    const int lane = tid & 63;
    const int wv = tid >> 6;
    const int node0 = blockIdx.x * 64;
    const int m = lane & 15;
    const int quad = lane >> 4;

    if (DO_STATS && tid < 128) st_part[tid] = 0.f;

    // A fragments (2 K-steps); invalid rows -> 0
    const int arow = node0 + wv * 16 + m;
    bfrag a0 = {0, 0, 0, 0, 0, 0, 0, 0}, a1 = {0, 0, 0, 0, 0, 0, 0, 0};
    if (arow < N) {
        const unsigned short* ab = in16 + (size_t)arow * EMB + quad * 8;
        a0 = *(const bfrag*)ab;
        a1 = *(const bfrag*)(ab + 32);
    }

    // B fragments from transposed bf16 weights (L2-hot) + MFMA
    const unsigned short* bb = Wt + (size_t)m * EMB + quad * 8;
    f32x4 acc[4];
#pragma unroll
    for (int c = 0; c < 4; c++) {
        bfrag b0 = *(const bfrag*)(bb + c * 16 * EMB);
        bfrag b1 = *(const bfrag*)(bb + c * 16 * EMB + 32);
        f32x4 z = {0.f, 0.f, 0.f, 0.f};
        z = __builtin_amdgcn_mfma_f32_16x16x32_bf16(a0, b0, z, 0, 0, 0);
        z = __builtin_amdgcn_mfma_f32_16x16x32_bf16(a1, b1, z, 0, 0, 0);
        acc[c] = z;
    }

    // epilogue: bias + write to LDS tile (invalid rows -> 0 so stats stay clean)
#pragma unroll
    for (int c = 0; c < 4; c++) {
        float bj = bias[c * 16 + m];
#pragma unroll
        for (int r = 0; r < 4; r++) {
            int row = wv * 16 + quad * 4 + r;
            float v = (node0 + row < N) ? (acc[c][r] + bj) : 0.f;
            tb[row * TS + c * 16 + m] = v;
        }
    }
    __syncthreads();

    if (DO_STATS) {
        float ssum = 0.f, ssq = 0.f;
#pragma unroll
        for (int i = 0; i < 16; i++) {
            float v = tb[(wv * 16 + i) * TS + lane];
            ssum += v;
            ssq = fmaf(v, v, ssq);
        }
        atomicAdd(&st_part[lane], ssum);
        atomicAdd(&st_part[64 + lane], ssq);
    }

    float4* out4 = (float4*)(out + (size_t)node0 * EMB);
#pragma unroll
    for (int it = 0; it < 4; it++) {
        int flat4 = it * 256 + tid;
        int nsub = flat4 >> 4;
        int c4 = flat4 & 15;
        if (node0 + nsub < N) {
            const float* s4 = tb + nsub * TS + c4 * 4;
            float4 o = make_float4(s4[0], s4[1], s4[2], s4[3]);
            out4[flat4] = o;
            if (B16OUT) {
                ushort4 ob;
                ob.x = f2b(o.x); ob.y = f2b(o.y);
                ob.z = f2b(o.z); ob.w = f2b(o.w);
                ((ushort4*)b16out)[(size_t)node0 * 16 + flat4] = ob;
            }
        }
    }

    if (DO_STATS) {
        __syncthreads();
        if (tid < 128) atomicAdd(&st_out[tid], st_part[tid]);
    }
}

// ---------------- BN + relu (between mm1 and mm2), bf16 out ----------------
__global__ void k_bn1(const float* __restrict__ t, const float* __restrict__ st,
                      const float* __restrict__ g, const float* __restrict__ be,
                      unsigned short* __restrict__ t16, float invN, int total4) {
    int stride = gridDim.x * blockDim.x;
    for (int i4 = blockIdx.x * blockDim.x + threadIdx.x; i4 < total4; i4 += stride) {
        int c = i4 & 15;
        float4 uv = ((const float4*)t)[i4];
        float4 sv = ((const float4*)st)[c];
        float4 qv = ((const float4*)(st + EMB))[c];
        float4 gv = ((const float4*)g)[c];
        float4 bv = ((const float4*)be)[c];
        ushort4 o;
#define BN1(comp, fld)                                                \
        {                                                             \
            float mm = sv.comp * invN;                                \
            float va = fmaf(qv.comp, invN, -mm * mm);                 \
            float rs = rsqrtf(va + BN_EPS);                           \
            float sc = rs * gv.comp;                                  \
            float sh = fmaf(-mm, sc, bv.comp);                        \
            o.fld = f2b(fmaxf(0.f, fmaf(uv.comp, sc, sh)));           \
        }
        BN1(x, x) BN1(y, y) BN1(z, z) BN1(w, w)
#undef BN1
        ((ushort4*)t16)[i4] = o;
    }
}

// ---------------- outer BN + relu + residual (+ bf16 copy) ----------------
__global__ void k_bnres(const float* __restrict__ u, const float* __restrict__ st,
                        const float* __restrict__ g, const float* __restrict__ be,
                        const float* __restrict__ hin, float* __restrict__ hout,
                        unsigned short* __restrict__ b16out,
                        float invN, int total4) {
    int stride = gridDim.x * blockDim.x;
    for (int i4 = blockIdx.x * blockDim.x + threadIdx.x; i4 < total4; i4 += stride) {
        int c = i4 & 15;
        float4 uv = ((const float4*)u)[i4];
        float4 hv = ((const float4*)hin)[i4];
        float4 sv = ((const float4*)st)[c];
        float4 qv = ((const float4*)(st + EMB))[c];
        float4 gv = ((const float4*)g)[c];
        float4 bv = ((const float4*)be)[c];
        float4 o;
#define BNR(comp)                                                     \
        {                                                             \
            float mm = sv.comp * invN;                                \
            float va = fmaf(qv.comp, invN, -mm * mm);                 \
            float rs = rsqrtf(va + BN_EPS);                           \
            float sc = rs * gv.comp;                                  \
            float sh = fmaf(-mm, sc, bv.comp);                        \
            float r  = fmaxf(0.f, fmaf(uv.comp, sc, sh));             \
            o.comp = r + hv.comp;                                     \
        }
        BNR(x) BNR(y) BNR(z) BNR(w)
#undef BNR
        ((float4*)hout)[i4] = o;
        if (b16out) {
            ushort4 ob;
            ob.x = f2b(o.x); ob.y = f2b(o.y);
            ob.z = f2b(o.z); ob.w = f2b(o.w);
            ((ushort4*)b16out)[i4] = ob;
        }
    }
}

// ---------------- launcher ----------------
extern "C" void kernel_launch(void* const* d_in, const int* in_sizes, int n_in,
                              void* d_out, int out_size, void* d_ws, size_t ws_size,
                              hipStream_t stream) {
    const float* x     = (const float*)d_in[0];
    const int*   ei    = (const int*)d_in[1];
    const float* ew    = (const float*)d_in[3];
    const float* ae_w  = (const float*)d_in[4];
    const float* ae_b  = (const float*)d_in[5];
    const float* W1    = (const float*)d_in[6];
    const float* b1    = (const float*)d_in[7];
    const float* g1    = (const float*)d_in[8];
    const float* be1   = (const float*)d_in[9];
    const float* W2    = (const float*)d_in[10];
    const float* b2    = (const float*)d_in[11];
    const float* g_out = (const float*)d_in[12];
    const float* be_out= (const float*)d_in[13];

    const int N = in_sizes[0] / EMB;
    const int E = in_sizes[3];
    const int L = in_sizes[6] / (EMB * EMB);
    const float invN = 1.0f / (float)N;
    const int NBUCK = (N + 255) >> BSH;

    uintptr_t p = (uintptr_t)d_ws;
    auto alloc = [&](size_t bytes) -> void* {
        p = (p + 255) & ~(uintptr_t)255;
        void* r = (void*)p;
        p += bytes;
        return r;
    };
    float* h     = (float*)alloc((size_t)N * EMB * 4);
    float* bufa  = (float*)alloc((size_t)N * EMB * 4);          // u (mm2 out)
    float* buft  = (float*)alloc((size_t)N * EMB * 4);          // t; aliases eG
    unsigned short* hb16  = (unsigned short*)alloc((size_t)N * EMB * 2);
    unsigned short* agg16 = (unsigned short*)alloc((size_t)N * EMB * 2);
    unsigned short* t16   = (unsigned short*)alloc((size_t)N * EMB * 2); // also x16
    unsigned short* Wt16  = (unsigned short*)alloc((size_t)(1 + 2 * L) * EMB * EMB * 2);
    int*   counts= (int*)alloc((size_t)N * 4);
    int*   rowst = (int*)alloc((size_t)N * 4);
    int*   bcnt  = (int*)alloc(256 * 4);
    int*   bbase = (int*)alloc(257 * 4);
    int*   bcur  = (int*)alloc(256 * 4);
    int2*  pairs = (int2*)alloc((size_t)E * 8);
    float* stats = (float*)alloc((size_t)L * 2 * 2 * EMB * 4);
    int2*  eG    = (int2*)buft;
    unsigned short* x16 = t16;
    (void)ws_size; (void)n_in; (void)out_size;

    const int nstats = L * 2 * 2 * EMB;
    int zgrid = ((NBUCK > nstats ? NBUCK : nstats) + 255) / 256;
    hipLaunchKernelGGL(k_zero, dim3(zgrid), dim3(256), 0, stream,
                       bcnt, stats, NBUCK, nstats);

    // prep: weights -> transposed bf16, x -> bf16
    const int nw = (1 + 2 * L) * EMB * EMB;
    hipLaunchKernelGGL(k_prep, dim3((nw + N * 16 + 255) / 256), dim3(256), 0, stream,
                       ae_w, W1, W2, x, Wt16, x16, L, N);

    const int ntiles = (N + 63) / 64;
    // encoder: h = x @ ae_w + ae_b  (MFMA, + bf16 copy)
    hipLaunchKernelGGL((k_mmx<false, true>), dim3(ntiles), dim3(256), 0, stream,
                       x16, Wt16, ae_b, h, (float*)nullptr, hb16, N);

    // CSR build: bucket hist -> scan -> compact -> per-bucket exact CSR
    hipLaunchKernelGGL(k_bhist, dim3(120), dim3(256), 0, stream, ei, bcnt, E, NBUCK);
    hipLaunchKernelGGL(k_bscan, dim3(1), dim3(256), 0, stream, bcnt, bbase, bcur, NBUCK);
    hipLaunchKernelGGL(k_part, dim3((E + CHUNK - 1) / CHUNK), dim3(256), 0, stream,
                       ei, ew, bcur, eG, E);
    hipLaunchKernelGGL(k_build, dim3(NBUCK), dim3(256), 0, stream,
                       eG, bbase, rowst, counts, pairs, N);

    for (int l = 0; l < L; l++) {
        float* stats1 = stats + (size_t)(l * 2 + 0) * 2 * EMB;
        float* stats2 = stats + (size_t)(l * 2 + 1) * 2 * EMB;

        // agg + self -> bf16 (mm1's A operand)
        hipLaunchKernelGGL(k_agg, dim3(2048), dim3(256), 0, stream,
                           hb16, h, rowst, counts, pairs, agg16, N);
        // t = agg @ W1 + b1   (+stats1)
        hipLaunchKernelGGL((k_mmx<true, false>), dim3(ntiles), dim3(256), 0, stream,
                           agg16, Wt16 + (size_t)(1 + l) * EMB * EMB, b1 + (size_t)l * EMB,
                           buft, stats1, (unsigned short*)nullptr, N);
        // t16 = relu(bn1(t))  (bf16, mm2's A operand)
        hipLaunchKernelGGL(k_bn1, dim3(1024), dim3(256), 0, stream,
                           buft, stats1, g1 + (size_t)l * EMB, be1 + (size_t)l * EMB,
                           t16, invN, N * 16);
        // u = t16 @ W2 + b2   (+stats2)
        hipLaunchKernelGGL((k_mmx<true, false>), dim3(ntiles), dim3(256), 0, stream,
                           t16, Wt16 + (size_t)(1 + L + l) * EMB * EMB, b2 + (size_t)l * EMB,
                           bufa, stats2, (unsigned short*)nullptr, N);
        // h = relu(bn2(u)) + h   (+ bf16 copy for next layer's gathers)
        float* hout = (l == L - 1) ? (float*)d_out : h;
        unsigned short* b16o = (l == L - 1) ? (unsigned short*)nullptr : hb16;
        hipLaunchKernelGGL(k_bnres, dim3(1024), dim3(256), 0, stream,
                           bufa, stats2, g_out + (size_t)l * EMB, be_out + (size_t)l * EMB,
                           h, hout, b16o, invN, N * 16);
    }
}

// Round 11
// 530.065 us; speedup vs baseline: 1.5996x; 1.0330x over previous
//
#include <hip/hip_runtime.h>
#include <stdint.h>

#define EMB 64
#define BN_EPS 1e-5f
#define BSH 8              // bucket = 256 consecutive dst nodes
#define CHUNK 4096         // edges per k_part block
#define TS 68              // LDS tile stride (floats): 2-way max bank aliasing

typedef short bfrag __attribute__((ext_vector_type(8)));   // 8 bf16 = 4 VGPRs
typedef float f32x4 __attribute__((ext_vector_type(4)));

#define IN_BF16  0
#define IN_F32   1
#define IN_F32BN 2

__device__ __forceinline__ unsigned short f2b(float x) {
    unsigned u = __float_as_uint(x);
    u += 0x7FFFu + ((u >> 16) & 1u);   // round-to-nearest-even
    return (unsigned short)(u >> 16);
}
__device__ __forceinline__ float b2f(unsigned short v) {
    return __uint_as_float(((unsigned)v) << 16);
}

// ---------------- prep: weights -> transposed bf16 + zero init -------------
__global__ void k_prep(const float* __restrict__ ae_w, const float* __restrict__ W1,
                       const float* __restrict__ W2,
                       unsigned short* __restrict__ Wt16,
                       int* __restrict__ bcnt, float* __restrict__ stats,
                       int L, int nb, int nstats) {
    int gid = blockIdx.x * blockDim.x + threadIdx.x;
    const int nw = (1 + 2 * L) * EMB * EMB;
    if (gid < nw) {
        int m = gid >> 12;
        int j = (gid >> 6) & 63;   // output col
        int k = gid & 63;          // input feature
        const float* src = (m == 0) ? ae_w
                         : (m <= L ? W1 + (size_t)(m - 1) * EMB * EMB
                                   : W2 + (size_t)(m - 1 - L) * EMB * EMB);
        Wt16[gid] = f2b(src[k * EMB + j]);   // Wt[m][j][k] = W[k][j]
    }
    if (gid < nb) bcnt[gid] = 0;
    if (gid < nstats) stats[gid] = 0.0f;
}

// ---------------- bucket histogram (dst read once, LDS-combined) ----------
__global__ void __launch_bounds__(256) k_bhist(const int* __restrict__ ei,
                                               int* __restrict__ bcnt,
                                               int E, int nb) {
    __shared__ int lh[256];
    const int tid = threadIdx.x;
    lh[tid] = 0;
    __syncthreads();
    int stride = gridDim.x * blockDim.x;
    for (int e = blockIdx.x * blockDim.x + tid; e < E; e += stride)
        atomicAdd(&lh[((unsigned)ei[E + e]) >> BSH], 1);
    __syncthreads();
    if (tid < nb && lh[tid]) atomicAdd(&bcnt[tid], lh[tid]);
}

// ---------------- single-block bucket scan ----------------
__global__ void __launch_bounds__(256) k_bscan(const int* __restrict__ bcnt,
                                               int* __restrict__ bbase,
                                               int* __restrict__ bcur, int nb) {
    __shared__ int a[256];
    const int t = threadIdx.x;
    int v = (t < nb) ? bcnt[t] : 0;
    a[t] = v;
    __syncthreads();
    for (int off = 1; off < 256; off <<= 1) {
        int x = (t >= off) ? a[t - off] : 0;
        __syncthreads();
        a[t] += x;
        __syncthreads();
    }
    int excl = a[t] - v;
    if (t < nb) { bbase[t] = excl; bcur[t] = excl; }
    if (t == nb - 1) bbase[nb] = a[t];
}

// ---------------- phase 1: compact edges into per-bucket runs --------------
__global__ void __launch_bounds__(256) k_part(
        const int* __restrict__ ei, const float* __restrict__ ew,
        int* __restrict__ bcur, int2* __restrict__ eG, int E) {
    __shared__ int lcnt[256], lbase[256], loff[256];
    const int tid = threadIdx.x;
    const int c0 = blockIdx.x * CHUNK;
    lcnt[tid] = 0;
    __syncthreads();
    int src[16], pk[16], g[16];
    float wt[16];
#pragma unroll
    for (int i = 0; i < 16; i++) {
        int e = c0 + i * 256 + tid;
        if (e < E) {
            int d = ei[E + e];
            src[i] = ei[e];
            wt[i] = ew[e];
            g[i] = ((unsigned)d) >> BSH;
            pk[i] = src[i] | ((d & 255) << 24);
            atomicAdd(&lcnt[g[i]], 1);
        } else g[i] = -1;
    }
    __syncthreads();
    if (lcnt[tid]) lbase[tid] = atomicAdd(&bcur[tid], lcnt[tid]);
    loff[tid] = 0;
    __syncthreads();
#pragma unroll
    for (int i = 0; i < 16; i++) {
        if (g[i] >= 0) {
            int pos = lbase[g[i]] + atomicAdd(&loff[g[i]], 1);
            eG[pos] = make_int2(pk[i], __float_as_int(wt[i]));
        }
    }
}

// ---------------- phase 2: exact CSR inside each bucket --------------------
__global__ void __launch_bounds__(256) k_build(
        const int2* __restrict__ eG, const int* __restrict__ bbase,
        int* __restrict__ rowst, int* __restrict__ counts,
        int2* __restrict__ pairs, int N) {
    __shared__ int lcnt[256], a[256], lcur[256];
    const int t = threadIdx.x;
    const int b = blockIdx.x;
    const int e0 = bbase[b], e1 = bbase[b + 1];
    lcnt[t] = 0;
    __syncthreads();
    for (int i = e0 + t; i < e1; i += 256)
        atomicAdd(&lcnt[((unsigned)eG[i].x) >> 24], 1);
    __syncthreads();
    int v = lcnt[t];
    a[t] = v;
    __syncthreads();
    for (int off = 1; off < 256; off <<= 1) {
        int x = (t >= off) ? a[t - off] : 0;
        __syncthreads();
        a[t] += x;
        __syncthreads();
    }
    int excl = a[t] - v;
    lcur[t] = excl;
    int node = (b << BSH) + t;
    if (node < N) { rowst[node] = e0 + excl; counts[node] = v; }
    __syncthreads();
    for (int i = e0 + t; i < e1; i += 256) {
        int2 p = eG[i];
        int loc = ((unsigned)p.x) >> 24;
        int pos = e0 + atomicAdd(&lcur[loc], 1);
        pairs[pos] = make_int2(p.x & 0x00FFFFFF, p.y);
    }
}

// ---------------- aggregation: wave-per-node, bf16 in AND out --------------
// Self term also from hb16 (agg output is bf16-rounded for mm1's A anyway).
__global__ void k_agg(const unsigned short* __restrict__ hb,
                      const int* __restrict__ rowst,
                      const int* __restrict__ counts, const int2* __restrict__ pairs,
                      unsigned short* __restrict__ out16, int N) {
    const int lane = threadIdx.x & 63;
    int wave = (blockIdx.x * blockDim.x + threadIdx.x) >> 6;
    const int nwaves = (gridDim.x * blockDim.x) >> 6;
    for (int node = wave; node < N; node += nwaves) {
        int un = __builtin_amdgcn_readfirstlane(node);
        int s = rowst[un];
        int end = s + counts[un];
        float a0 = 0.f, a1 = 0.f, a2 = 0.f, a3 = 0.f;
        float a4 = 0.f, a5 = 0.f, a6 = 0.f, a7 = 0.f;
        for (int e = s; e < end; e += 8) {
#define SLOT(K, ACC)                                                       \
            {                                                              \
                int idx = e + K;                                           \
                bool ok = idx < end;                                       \
                int2 p = pairs[ok ? idx : s];                              \
                float w = ok ? __int_as_float(p.y) : 0.f;                  \
                float vv = b2f(hb[(size_t)p.x * EMB + lane]);              \
                ACC = fmaf(w, vv, ACC);                                    \
            }
            SLOT(0, a0) SLOT(1, a1) SLOT(2, a2) SLOT(3, a3)
            SLOT(4, a4) SLOT(5, a5) SLOT(6, a6) SLOT(7, a7)
#undef SLOT
        }
        float self = b2f(hb[(size_t)un * EMB + lane]);
        float sum = (((a0 + a1) + (a2 + a3)) + ((a4 + a5) + (a6 + a7))) + self;
        out16[(size_t)un * EMB + lane] = f2b(sum);   // 128B/row, full-line
    }
}

// ---------------- MFMA matmul: block = 64-node tile, 4 waves ---------------
// INMODE: IN_BF16 (bf16 rows), IN_F32 (fp32 -> convert), IN_F32BN (fp32 ->
// BN+relu via LDS coeff table -> convert). 4 col-tiles x 2 K-steps of
// v_mfma_f32_16x16x32_bf16, fp32 accumulate. A[m=lane&15][k=quad*8+j],
// C col=lane&15,row=quad*4+reg. Epilogue via stride-68 LDS tile ->
// coalesced flush + stats (+ optional bf16 pack).
template <int INMODE, bool DO_STATS, bool B16OUT>
__global__ void __launch_bounds__(256) k_mmx(
        const void* __restrict__ in_v, const unsigned short* __restrict__ Wt,
        const float* __restrict__ bias, const float* __restrict__ stats,
        const float* __restrict__ g, const float* __restrict__ be, float invN,
        float* __restrict__ out, float* __restrict__ st_out,
        unsigned short* __restrict__ b16out, int N) {
    __shared__ float tb[64 * TS];
    __shared__ float st_part[128];
    __shared__ float scs[EMB], shs[EMB];
    const int tid = threadIdx.x;
    const int lane = tid & 63;
    const int wv = tid >> 6;
    const int node0 = blockIdx.x * 64;
    const int m = lane & 15;
    const int quad = lane >> 4;

    if (DO_STATS && tid < 128) st_part[tid] = 0.f;
    if (INMODE == IN_F32BN) {
        if (tid < EMB) {
            float mm = stats[tid] * invN;
            float va = fmaf(stats[EMB + tid], invN, -mm * mm);
            float rs = rsqrtf(va + BN_EPS);
            float sc = rs * g[tid];
            scs[tid] = sc;
            shs[tid] = fmaf(-mm, sc, be[tid]);
        }
        __syncthreads();
    }

    // A fragments (2 K-steps); invalid rows -> 0
    const int arow = node0 + wv * 16 + m;
    bfrag a0 = {0, 0, 0, 0, 0, 0, 0, 0}, a1 = {0, 0, 0, 0, 0, 0, 0, 0};
    if (arow < N) {
        if (INMODE == IN_BF16) {
            const unsigned short* ab =
                (const unsigned short*)in_v + (size_t)arow * EMB + quad * 8;
            a0 = *(const bfrag*)ab;
            a1 = *(const bfrag*)(ab + 32);
        } else {
            const float* af = (const float*)in_v + (size_t)arow * EMB + quad * 8;
#pragma unroll
            for (int j = 0; j < 8; j++) {
                int k0 = quad * 8 + j;
                float v0 = af[j], v1 = af[32 + j];
                if (INMODE == IN_F32BN) {
                    v0 = fmaxf(0.f, fmaf(v0, scs[k0], shs[k0]));
                    v1 = fmaxf(0.f, fmaf(v1, scs[k0 + 32], shs[k0 + 32]));
                }
                a0[j] = (short)f2b(v0);
                a1[j] = (short)f2b(v1);
            }
        }
    }

    // B fragments from transposed bf16 weights (L2-hot) + MFMA
    const unsigned short* bb = Wt + (size_t)m * EMB + quad * 8;
    f32x4 acc[4];
#pragma unroll
    for (int c = 0; c < 4; c++) {
        bfrag b0 = *(const bfrag*)(bb + c * 16 * EMB);
        bfrag b1 = *(const bfrag*)(bb + c * 16 * EMB + 32);
        f32x4 z = {0.f, 0.f, 0.f, 0.f};
        z = __builtin_amdgcn_mfma_f32_16x16x32_bf16(a0, b0, z, 0, 0, 0);
        z = __builtin_amdgcn_mfma_f32_16x16x32_bf16(a1, b1, z, 0, 0, 0);
        acc[c] = z;
    }

    // epilogue: bias + write to LDS tile (invalid rows -> 0 so stats stay clean)
#pragma unroll
    for (int c = 0; c < 4; c++) {
        float bj = bias[c * 16 + m];
#pragma unroll
        for (int r = 0; r < 4; r++) {
            int row = wv * 16 + quad * 4 + r;
            float v = (node0 + row < N) ? (acc[c][r] + bj) : 0.f;
            tb[row * TS + c * 16 + m] = v;
        }
    }
    __syncthreads();

    if (DO_STATS) {
        float ssum = 0.f, ssq = 0.f;
#pragma unroll
        for (int i = 0; i < 16; i++) {
            float v = tb[(wv * 16 + i) * TS + lane];
            ssum += v;
            ssq = fmaf(v, v, ssq);
        }
        atomicAdd(&st_part[lane], ssum);
        atomicAdd(&st_part[64 + lane], ssq);
    }

    float4* out4 = (float4*)(out + (size_t)node0 * EMB);
#pragma unroll
    for (int it = 0; it < 4; it++) {
        int flat4 = it * 256 + tid;
        int nsub = flat4 >> 4;
        int c4 = flat4 & 15;
        if (node0 + nsub < N) {
            const float* s4 = tb + nsub * TS + c4 * 4;
            float4 o = make_float4(s4[0], s4[1], s4[2], s4[3]);
            out4[flat4] = o;
            if (B16OUT) {
                ushort4 ob;
                ob.x = f2b(o.x); ob.y = f2b(o.y);
                ob.z = f2b(o.z); ob.w = f2b(o.w);
                ((ushort4*)b16out)[(size_t)node0 * 16 + flat4] = ob;
            }
        }
    }

    if (DO_STATS) {
        __syncthreads();
        if (tid < 128) atomicAdd(&st_out[tid], st_part[tid]);
    }
}

// ---------------- outer BN + relu + residual (+ bf16 copy) ----------------
__global__ void k_bnres(const float* __restrict__ u, const float* __restrict__ st,
                        const float* __restrict__ g, const float* __restrict__ be,
                        const float* __restrict__ hin, float* __restrict__ hout,
                        unsigned short* __restrict__ b16out,
                        float invN, int total4) {
    int stride = gridDim.x * blockDim.x;
    for (int i4 = blockIdx.x * blockDim.x + threadIdx.x; i4 < total4; i4 += stride) {
        int c = i4 & 15;
        float4 uv = ((const float4*)u)[i4];
        float4 hv = ((const float4*)hin)[i4];
        float4 sv = ((const float4*)st)[c];
        float4 qv = ((const float4*)(st + EMB))[c];
        float4 gv = ((const float4*)g)[c];
        float4 bv = ((const float4*)be)[c];
        float4 o;
#define BNR(comp)                                                     \
        {                                                             \
            float mm = sv.comp * invN;                                \
            float va = fmaf(qv.comp, invN, -mm * mm);                 \
            float rs = rsqrtf(va + BN_EPS);                           \
            float sc = rs * gv.comp;                                  \
            float sh = fmaf(-mm, sc, bv.comp);                        \
            float r  = fmaxf(0.f, fmaf(uv.comp, sc, sh));             \
            o.comp = r + hv.comp;                                     \
        }
        BNR(x) BNR(y) BNR(z) BNR(w)
#undef BNR
        ((float4*)hout)[i4] = o;
        if (b16out) {
            ushort4 ob;
            ob.x = f2b(o.x); ob.y = f2b(o.y);
            ob.z = f2b(o.z); ob.w = f2b(o.w);
            ((ushort4*)b16out)[i4] = ob;
        }
    }
}

// ---------------- launcher ----------------
extern "C" void kernel_launch(void* const* d_in, const int* in_sizes, int n_in,
                              void* d_out, int out_size, void* d_ws, size_t ws_size,
                              hipStream_t stream) {
    const float* x     = (const float*)d_in[0];
    const int*   ei    = (const int*)d_in[1];
    const float* ew    = (const float*)d_in[3];
    const float* ae_w  = (const float*)d_in[4];
    const float* ae_b  = (const float*)d_in[5];
    const float* W1    = (const float*)d_in[6];
    const float* b1    = (const float*)d_in[7];
    const float* g1    = (const float*)d_in[8];
    const float* be1   = (const float*)d_in[9];
    const float* W2    = (const float*)d_in[10];
    const float* b2    = (const float*)d_in[11];
    const float* g_out = (const float*)d_in[12];
    const float* be_out= (const float*)d_in[13];

    const int N = in_sizes[0] / EMB;
    const int E = in_sizes[3];
    const int L = in_sizes[6] / (EMB * EMB);
    const float invN = 1.0f / (float)N;
    const int NBUCK = (N + 255) >> BSH;

    uintptr_t p = (uintptr_t)d_ws;
    auto alloc = [&](size_t bytes) -> void* {
        p = (p + 255) & ~(uintptr_t)255;
        void* r = (void*)p;
        p += bytes;
        return r;
    };
    float* h     = (float*)alloc((size_t)N * EMB * 4);
    float* bufa  = (float*)alloc((size_t)N * EMB * 4);          // u (mm2 out)
    float* buft  = (float*)alloc((size_t)N * EMB * 4);          // t; aliases eG
    unsigned short* hb16  = (unsigned short*)alloc((size_t)N * EMB * 2);
    unsigned short* agg16 = (unsigned short*)alloc((size_t)N * EMB * 2);
    unsigned short* Wt16  = (unsigned short*)alloc((size_t)(1 + 2 * L) * EMB * EMB * 2);
    int*   counts= (int*)alloc((size_t)N * 4);
    int*   rowst = (int*)alloc((size_t)N * 4);
    int*   bcnt  = (int*)alloc(256 * 4);
    int*   bbase = (int*)alloc(257 * 4);
    int*   bcur  = (int*)alloc(256 * 4);
    int2*  pairs = (int2*)alloc((size_t)E * 8);
    float* stats = (float*)alloc((size_t)L * 2 * 2 * EMB * 4);
    int2*  eG    = (int2*)buft;
    (void)ws_size; (void)n_in; (void)out_size;

    // prep: weights -> transposed bf16, zero bcnt/stats
    const int nw = (1 + 2 * L) * EMB * EMB;
    const int nstats = L * 2 * 2 * EMB;
    hipLaunchKernelGGL(k_prep, dim3((nw + 255) / 256), dim3(256), 0, stream,
                       ae_w, W1, W2, Wt16, bcnt, stats, L, NBUCK, nstats);

    const int ntiles = (N + 63) / 64;
    // encoder: h = x @ ae_w + ae_b  (MFMA, fp32 in, + bf16 copy)
    hipLaunchKernelGGL((k_mmx<IN_F32, false, true>), dim3(ntiles), dim3(256), 0, stream,
                       x, Wt16, ae_b, (const float*)nullptr, (const float*)nullptr,
                       (const float*)nullptr, 0.f, h, (float*)nullptr, hb16, N);

    // CSR build: bucket hist -> scan -> compact -> per-bucket exact CSR
    hipLaunchKernelGGL(k_bhist, dim3(120), dim3(256), 0, stream, ei, bcnt, E, NBUCK);
    hipLaunchKernelGGL(k_bscan, dim3(1), dim3(256), 0, stream, bcnt, bbase, bcur, NBUCK);
    hipLaunchKernelGGL(k_part, dim3((E + CHUNK - 1) / CHUNK), dim3(256), 0, stream,
                       ei, ew, bcur, eG, E);
    hipLaunchKernelGGL(k_build, dim3(NBUCK), dim3(256), 0, stream,
                       eG, bbase, rowst, counts, pairs, N);

    for (int l = 0; l < L; l++) {
        float* stats1 = stats + (size_t)(l * 2 + 0) * 2 * EMB;
        float* stats2 = stats + (size_t)(l * 2 + 1) * 2 * EMB;

        // agg + self -> bf16 (mm1's A operand)
        hipLaunchKernelGGL(k_agg, dim3(2048), dim3(256), 0, stream,
                           hb16, rowst, counts, pairs, agg16, N);
        // t = agg @ W1 + b1   (+stats1)
        hipLaunchKernelGGL((k_mmx<IN_BF16, true, false>), dim3(ntiles), dim3(256), 0, stream,
                           agg16, Wt16 + (size_t)(1 + l) * EMB * EMB, b1 + (size_t)l * EMB,
                           (const float*)nullptr, (const float*)nullptr,
                           (const float*)nullptr, 0.f,
                           buft, stats1, (unsigned short*)nullptr, N);
        // u = relu(bn1(t)) @ W2 + b2   (BN fused into A-fragment build, +stats2)
        hipLaunchKernelGGL((k_mmx<IN_F32BN, true, false>), dim3(ntiles), dim3(256), 0, stream,
                           buft, Wt16 + (size_t)(1 + L + l) * EMB * EMB, b2 + (size_t)l * EMB,
                           stats1, g1 + (size_t)l * EMB, be1 + (size_t)l * EMB, invN,
                           bufa, stats2, (unsigned short*)nullptr, N);
        // h = relu(bn2(u)) + h   (+ bf16 copy for next layer's gathers)
        float* hout = (l == L - 1) ? (float*)d_out : h;
        unsigned short* b16o = (l == L - 1) ? (unsigned short*)nullptr : hb16;
        hipLaunchKernelGGL(k_bnres, dim3(1024), dim3(256), 0, stream,
                           bufa, stats2, g_out + (size_t)l * EMB, be_out + (size_t)l * EMB,
                           h, hout, b16o, invN, N * 16);
    }
}

// Round 12
// 524.317 us; speedup vs baseline: 1.6171x; 1.0110x over previous
//
#include <hip/hip_runtime.h>
#include <stdint.h>

#define EMB 64
#define BN_EPS 1e-5f
#define BSH 8              // bucket = 256 consecutive dst nodes
#define CHUNK 4096         // edges per k_part block
#define TS 68              // LDS tile stride (floats): 2-way max bank aliasing

typedef short bfrag __attribute__((ext_vector_type(8)));   // 8 bf16 = 4 VGPRs
typedef float f32x4 __attribute__((ext_vector_type(4)));

#define IN_F32    0
#define IN_BF16   1
#define IN_BF16BN 2

__device__ __forceinline__ unsigned short f2b(float x) {
    unsigned u = __float_as_uint(x);
    u += 0x7FFFu + ((u >> 16) & 1u);   // round-to-nearest-even
    return (unsigned short)(u >> 16);
}
__device__ __forceinline__ float b2f(unsigned short v) {
    return __uint_as_float(((unsigned)v) << 16);
}

// ---------------- prep: weights -> transposed bf16 + zero init -------------
__global__ void k_prep(const float* __restrict__ ae_w, const float* __restrict__ W1,
                       const float* __restrict__ W2,
                       unsigned short* __restrict__ Wt16,
                       int* __restrict__ bcnt, float* __restrict__ stats,
                       int L, int nb, int nstats) {
    int gid = blockIdx.x * blockDim.x + threadIdx.x;
    const int nw = (1 + 2 * L) * EMB * EMB;
    if (gid < nw) {
        int m = gid >> 12;
        int j = (gid >> 6) & 63;   // output col
        int k = gid & 63;          // input feature
        const float* src = (m == 0) ? ae_w
                         : (m <= L ? W1 + (size_t)(m - 1) * EMB * EMB
                                   : W2 + (size_t)(m - 1 - L) * EMB * EMB);
        Wt16[gid] = f2b(src[k * EMB + j]);   // Wt[m][j][k] = W[k][j]
    }
    if (gid < nb) bcnt[gid] = 0;
    if (gid < nstats) stats[gid] = 0.0f;
}

// ---------------- bucket histogram (dst read once, LDS-combined) ----------
__global__ void __launch_bounds__(256) k_bhist(const int* __restrict__ ei,
                                               int* __restrict__ bcnt,
                                               int E, int nb) {
    __shared__ int lh[256];
    const int tid = threadIdx.x;
    lh[tid] = 0;
    __syncthreads();
    int stride = gridDim.x * blockDim.x;
    for (int e = blockIdx.x * blockDim.x + tid; e < E; e += stride)
        atomicAdd(&lh[((unsigned)ei[E + e]) >> BSH], 1);
    __syncthreads();
    if (tid < nb && lh[tid]) atomicAdd(&bcnt[tid], lh[tid]);
}

// ---------------- single-block bucket scan ----------------
__global__ void __launch_bounds__(256) k_bscan(const int* __restrict__ bcnt,
                                               int* __restrict__ bbase,
                                               int* __restrict__ bcur, int nb) {
    __shared__ int a[256];
    const int t = threadIdx.x;
    int v = (t < nb) ? bcnt[t] : 0;
    a[t] = v;
    __syncthreads();
    for (int off = 1; off < 256; off <<= 1) {
        int x = (t >= off) ? a[t - off] : 0;
        __syncthreads();
        a[t] += x;
        __syncthreads();
    }
    int excl = a[t] - v;
    if (t < nb) { bbase[t] = excl; bcur[t] = excl; }
    if (t == nb - 1) bbase[nb] = a[t];
}

// ---------------- phase 1: compact edges into per-bucket runs --------------
__global__ void __launch_bounds__(256) k_part(
        const int* __restrict__ ei, const float* __restrict__ ew,
        int* __restrict__ bcur, int2* __restrict__ eG, int E) {
    __shared__ int lcnt[256], lbase[256], loff[256];
    const int tid = threadIdx.x;
    const int c0 = blockIdx.x * CHUNK;
    lcnt[tid] = 0;
    __syncthreads();
    int src[16], pk[16], g[16];
    float wt[16];
#pragma unroll
    for (int i = 0; i < 16; i++) {
        int e = c0 + i * 256 + tid;
        if (e < E) {
            int d = ei[E + e];
            src[i] = ei[e];
            wt[i] = ew[e];
            g[i] = ((unsigned)d) >> BSH;
            pk[i] = src[i] | ((d & 255) << 24);
            atomicAdd(&lcnt[g[i]], 1);
        } else g[i] = -1;
    }
    __syncthreads();
    if (lcnt[tid]) lbase[tid] = atomicAdd(&bcur[tid], lcnt[tid]);
    loff[tid] = 0;
    __syncthreads();
#pragma unroll
    for (int i = 0; i < 16; i++) {
        if (g[i] >= 0) {
            int pos = lbase[g[i]] + atomicAdd(&loff[g[i]], 1);
            eG[pos] = make_int2(pk[i], __float_as_int(wt[i]));
        }
    }
}

// ---------------- phase 2: exact CSR inside each bucket --------------------
__global__ void __launch_bounds__(256) k_build(
        const int2* __restrict__ eG, const int* __restrict__ bbase,
        int* __restrict__ rowst, int* __restrict__ counts,
        int2* __restrict__ pairs, int N) {
    __shared__ int lcnt[256], a[256], lcur[256];
    const int t = threadIdx.x;
    const int b = blockIdx.x;
    const int e0 = bbase[b], e1 = bbase[b + 1];
    lcnt[t] = 0;
    __syncthreads();
    for (int i = e0 + t; i < e1; i += 256)
        atomicAdd(&lcnt[((unsigned)eG[i].x) >> 24], 1);
    __syncthreads();
    int v = lcnt[t];
    a[t] = v;
    __syncthreads();
    for (int off = 1; off < 256; off <<= 1) {
        int x = (t >= off) ? a[t - off] : 0;
        __syncthreads();
        a[t] += x;
        __syncthreads();
    }
    int excl = a[t] - v;
    lcur[t] = excl;
    int node = (b << BSH) + t;
    if (node < N) { rowst[node] = e0 + excl; counts[node] = v; }
    __syncthreads();
    for (int i = e0 + t; i < e1; i += 256) {
        int2 p = eG[i];
        int loc = ((unsigned)p.x) >> 24;
        int pos = e0 + atomicAdd(&lcur[loc], 1);
        pairs[pos] = make_int2(p.x & 0x00FFFFFF, p.y);
    }
}

// ---------------- aggregation: wave-per-node, bf16 in AND out --------------
__global__ void k_agg(const unsigned short* __restrict__ hb,
                      const int* __restrict__ rowst,
                      const int* __restrict__ counts, const int2* __restrict__ pairs,
                      unsigned short* __restrict__ out16, int N) {
    const int lane = threadIdx.x & 63;
    int wave = (blockIdx.x * blockDim.x + threadIdx.x) >> 6;
    const int nwaves = (gridDim.x * blockDim.x) >> 6;
    for (int node = wave; node < N; node += nwaves) {
        int un = __builtin_amdgcn_readfirstlane(node);
        int s = rowst[un];
        int end = s + counts[un];
        float a0 = 0.f, a1 = 0.f, a2 = 0.f, a3 = 0.f;
        float a4 = 0.f, a5 = 0.f, a6 = 0.f, a7 = 0.f;
        for (int e = s; e < end; e += 8) {
#define SLOT(K, ACC)                                                       \
            {                                                              \
                int idx = e + K;                                           \
                bool ok = idx < end;                                       \
                int2 p = pairs[ok ? idx : s];                              \
                float w = ok ? __int_as_float(p.y) : 0.f;                  \
                float vv = b2f(hb[(size_t)p.x * EMB + lane]);              \
                ACC = fmaf(w, vv, ACC);                                    \
            }
            SLOT(0, a0) SLOT(1, a1) SLOT(2, a2) SLOT(3, a3)
            SLOT(4, a4) SLOT(5, a5) SLOT(6, a6) SLOT(7, a7)
#undef SLOT
        }
        float self = b2f(hb[(size_t)un * EMB + lane]);
        float sum = (((a0 + a1) + (a2 + a3)) + ((a4 + a5) + (a6 + a7))) + self;
        out16[(size_t)un * EMB + lane] = f2b(sum);   // 128B/row, full-line
    }
}

// ---------------- MFMA matmul: block = 64-node tile, 4 waves ---------------
// INMODE: IN_F32 (fp32 rows -> convert), IN_BF16 (bf16 rows), IN_BF16BN
// (bf16 rows -> BN+relu via LDS coeff table). Output bf16 ONLY, staged via
// fp32 LDS tile (stats computed fp32-exact before rounding). 4 col-tiles x
// 2 K-steps of v_mfma_f32_16x16x32_bf16; A[m=lane&15][k=quad*8+j],
// C col=lane&15, row=quad*4+reg.
template <int INMODE, bool DO_STATS>
__global__ void __launch_bounds__(256) k_mmx(
        const void* __restrict__ in_v, const unsigned short* __restrict__ Wt,
        const float* __restrict__ bias, const float* __restrict__ stats,
        const float* __restrict__ g, const float* __restrict__ be, float invN,
        unsigned short* __restrict__ out16, float* __restrict__ st_out, int N) {
    __shared__ float tb[64 * TS];
    __shared__ float st_part[128];
    __shared__ float scs[EMB], shs[EMB];
    const int tid = threadIdx.x;
    const int lane = tid & 63;
    const int wv = tid >> 6;
    const int node0 = blockIdx.x * 64;
    const int m = lane & 15;
    const int quad = lane >> 4;

    if (DO_STATS && tid < 128) st_part[tid] = 0.f;
    if (INMODE == IN_BF16BN) {
        if (tid < EMB) {
            float mm = stats[tid] * invN;
            float va = fmaf(stats[EMB + tid], invN, -mm * mm);
            float rs = rsqrtf(va + BN_EPS);
            float sc = rs * g[tid];
            scs[tid] = sc;
            shs[tid] = fmaf(-mm, sc, be[tid]);
        }
        __syncthreads();
    }

    // A fragments (2 K-steps); invalid rows -> 0
    const int arow = node0 + wv * 16 + m;
    bfrag a0 = {0, 0, 0, 0, 0, 0, 0, 0}, a1 = {0, 0, 0, 0, 0, 0, 0, 0};
    if (arow < N) {
        if (INMODE == IN_BF16) {
            const unsigned short* ab =
                (const unsigned short*)in_v + (size_t)arow * EMB + quad * 8;
            a0 = *(const bfrag*)ab;
            a1 = *(const bfrag*)(ab + 32);
        } else if (INMODE == IN_BF16BN) {
            const unsigned short* ab =
                (const unsigned short*)in_v + (size_t)arow * EMB + quad * 8;
            bfrag r0 = *(const bfrag*)ab;
            bfrag r1 = *(const bfrag*)(ab + 32);
#pragma unroll
            for (int j = 0; j < 8; j++) {
                int k0 = quad * 8 + j;
                float v0 = b2f((unsigned short)r0[j]);
                float v1 = b2f((unsigned short)r1[j]);
                v0 = fmaxf(0.f, fmaf(v0, scs[k0], shs[k0]));
                v1 = fmaxf(0.f, fmaf(v1, scs[k0 + 32], shs[k0 + 32]));
                a0[j] = (short)f2b(v0);
                a1[j] = (short)f2b(v1);
            }
        } else {   // IN_F32
            const float* af = (const float*)in_v + (size_t)arow * EMB + quad * 8;
#pragma unroll
            for (int j = 0; j < 8; j++) {
                a0[j] = (short)f2b(af[j]);
                a1[j] = (short)f2b(af[32 + j]);
            }
        }
    }

    // B fragments from transposed bf16 weights (L2-hot) + MFMA
    const unsigned short* bb = Wt + (size_t)m * EMB + quad * 8;
    f32x4 acc[4];
#pragma unroll
    for (int c = 0; c < 4; c++) {
        bfrag b0 = *(const bfrag*)(bb + c * 16 * EMB);
        bfrag b1 = *(const bfrag*)(bb + c * 16 * EMB + 32);
        f32x4 z = {0.f, 0.f, 0.f, 0.f};
        z = __builtin_amdgcn_mfma_f32_16x16x32_bf16(a0, b0, z, 0, 0, 0);
        z = __builtin_amdgcn_mfma_f32_16x16x32_bf16(a1, b1, z, 0, 0, 0);
        acc[c] = z;
    }

    // epilogue: bias + fp32 LDS tile (invalid rows -> 0 so stats stay clean)
#pragma unroll
    for (int c = 0; c < 4; c++) {
        float bj = bias[c * 16 + m];
#pragma unroll
        for (int r = 0; r < 4; r++) {
            int row = wv * 16 + quad * 4 + r;
            float v = (node0 + row < N) ? (acc[c][r] + bj) : 0.f;
            tb[row * TS + c * 16 + m] = v;
        }
    }
    __syncthreads();

    if (DO_STATS) {
        float ssum = 0.f, ssq = 0.f;
#pragma unroll
        for (int i = 0; i < 16; i++) {
            float v = tb[(wv * 16 + i) * TS + lane];
            ssum += v;
            ssq = fmaf(v, v, ssq);
        }
        atomicAdd(&st_part[lane], ssum);
        atomicAdd(&st_part[64 + lane], ssq);
    }

    // coalesced bf16 flush: 1024 ushort4 per tile
    ushort4* o4 = (ushort4*)(out16 + (size_t)node0 * EMB);
#pragma unroll
    for (int it = 0; it < 4; it++) {
        int flat4 = it * 256 + tid;
        int nsub = flat4 >> 4;
        int c4 = flat4 & 15;
        if (node0 + nsub < N) {
            const float* s4 = tb + nsub * TS + c4 * 4;
            ushort4 o;
            o.x = f2b(s4[0]); o.y = f2b(s4[1]);
            o.z = f2b(s4[2]); o.w = f2b(s4[3]);
            o4[flat4] = o;
        }
    }

    if (DO_STATS) {
        __syncthreads();
        if (tid < 128) atomicAdd(&st_out[tid], st_part[tid]);
    }
}

// ---------------- outer BN + relu + residual ------------------------------
// !LAST: hb16 <- bf16(relu(bn(u)) + h)   (in place over hb16)
//  LAST: out32 <- relu(bn(u)) + h        (fp32 d_out)
template <bool LAST>
__global__ void k_bnres(const unsigned short* __restrict__ u16,
                        const float* __restrict__ st,
                        const float* __restrict__ g, const float* __restrict__ be,
                        unsigned short* __restrict__ hb16, float* __restrict__ out32,
                        float invN, int total4) {
    int stride = gridDim.x * blockDim.x;
    for (int i4 = blockIdx.x * blockDim.x + threadIdx.x; i4 < total4; i4 += stride) {
        int c = i4 & 15;
        ushort4 uv = ((const ushort4*)u16)[i4];
        ushort4 hv = ((const ushort4*)hb16)[i4];
        float4 sv = ((const float4*)st)[c];
        float4 qv = ((const float4*)(st + EMB))[c];
        float4 gv = ((const float4*)g)[c];
        float4 bv = ((const float4*)be)[c];
        float4 o;
#define BNR(comp, fld)                                                \
        {                                                             \
            float mm = sv.comp * invN;                                \
            float va = fmaf(qv.comp, invN, -mm * mm);                 \
            float rs = rsqrtf(va + BN_EPS);                           \
            float sc = rs * gv.comp;                                  \
            float sh = fmaf(-mm, sc, bv.comp);                        \
            float r  = fmaxf(0.f, fmaf(b2f(uv.fld), sc, sh));         \
            o.comp = r + b2f(hv.fld);                                 \
        }
        BNR(x, x) BNR(y, y) BNR(z, z) BNR(w, w)
#undef BNR
        if (LAST) {
            ((float4*)out32)[i4] = o;
        } else {
            ushort4 ob;
            ob.x = f2b(o.x); ob.y = f2b(o.y);
            ob.z = f2b(o.z); ob.w = f2b(o.w);
            ((ushort4*)hb16)[i4] = ob;
        }
    }
}

// ---------------- launcher ----------------
extern "C" void kernel_launch(void* const* d_in, const int* in_sizes, int n_in,
                              void* d_out, int out_size, void* d_ws, size_t ws_size,
                              hipStream_t stream) {
    const float* x     = (const float*)d_in[0];
    const int*   ei    = (const int*)d_in[1];
    const float* ew    = (const float*)d_in[3];
    const float* ae_w  = (const float*)d_in[4];
    const float* ae_b  = (const float*)d_in[5];
    const float* W1    = (const float*)d_in[6];
    const float* b1    = (const float*)d_in[7];
    const float* g1    = (const float*)d_in[8];
    const float* be1   = (const float*)d_in[9];
    const float* W2    = (const float*)d_in[10];
    const float* b2    = (const float*)d_in[11];
    const float* g_out = (const float*)d_in[12];
    const float* be_out= (const float*)d_in[13];

    const int N = in_sizes[0] / EMB;
    const int E = in_sizes[3];
    const int L = in_sizes[6] / (EMB * EMB);
    const float invN = 1.0f / (float)N;
    const int NBUCK = (N + 255) >> BSH;

    uintptr_t p = (uintptr_t)d_ws;
    auto alloc = [&](size_t bytes) -> void* {
        p = (p + 255) & ~(uintptr_t)255;
        void* r = (void*)p;
        p += bytes;
        return r;
    };
    unsigned short* hb16 = (unsigned short*)alloc((size_t)N * EMB * 2); // residual h
    unsigned short* b16a = (unsigned short*)alloc((size_t)N * EMB * 2); // agg16 / u16
    unsigned short* t16  = (unsigned short*)alloc((size_t)N * EMB * 2); // t
    unsigned short* Wt16 = (unsigned short*)alloc((size_t)(1 + 2 * L) * EMB * EMB * 2);
    int*   counts= (int*)alloc((size_t)N * 4);
    int*   rowst = (int*)alloc((size_t)N * 4);
    int*   bcnt  = (int*)alloc(256 * 4);
    int*   bbase = (int*)alloc(257 * 4);
    int*   bcur  = (int*)alloc(256 * 4);
    int2*  pairs = (int2*)alloc((size_t)E * 8);
    int2*  eG    = (int2*)alloc((size_t)E * 8);
    float* stats = (float*)alloc((size_t)L * 2 * 2 * EMB * 4);
    (void)ws_size; (void)n_in; (void)out_size;

    // prep: weights -> transposed bf16, zero bcnt/stats
    const int nw = (1 + 2 * L) * EMB * EMB;
    const int nstats = L * 2 * 2 * EMB;
    hipLaunchKernelGGL(k_prep, dim3((nw + 255) / 256), dim3(256), 0, stream,
                       ae_w, W1, W2, Wt16, bcnt, stats, L, NBUCK, nstats);

    const int ntiles = (N + 63) / 64;
    // encoder: hb16 = bf16(x @ ae_w + ae_b)
    hipLaunchKernelGGL((k_mmx<IN_F32, false>), dim3(ntiles), dim3(256), 0, stream,
                       x, Wt16, ae_b, (const float*)nullptr, (const float*)nullptr,
                       (const float*)nullptr, 0.f, hb16, (float*)nullptr, N);

    // CSR build: bucket hist -> scan -> compact -> per-bucket exact CSR
    hipLaunchKernelGGL(k_bhist, dim3(120), dim3(256), 0, stream, ei, bcnt, E, NBUCK);
    hipLaunchKernelGGL(k_bscan, dim3(1), dim3(256), 0, stream, bcnt, bbase, bcur, NBUCK);
    hipLaunchKernelGGL(k_part, dim3((E + CHUNK - 1) / CHUNK), dim3(256), 0, stream,
                       ei, ew, bcur, eG, E);
    hipLaunchKernelGGL(k_build, dim3(NBUCK), dim3(256), 0, stream,
                       eG, bbase, rowst, counts, pairs, N);

    for (int l = 0; l < L; l++) {
        float* stats1 = stats + (size_t)(l * 2 + 0) * 2 * EMB;
        float* stats2 = stats + (size_t)(l * 2 + 1) * 2 * EMB;

        // agg + self -> bf16 (mm1's A operand)
        hipLaunchKernelGGL(k_agg, dim3(2048), dim3(256), 0, stream,
                           hb16, rowst, counts, pairs, b16a, N);
        // t16 = bf16(agg @ W1 + b1)   (+stats1, fp32-exact)
        hipLaunchKernelGGL((k_mmx<IN_BF16, true>), dim3(ntiles), dim3(256), 0, stream,
                           b16a, Wt16 + (size_t)(1 + l) * EMB * EMB, b1 + (size_t)l * EMB,
                           (const float*)nullptr, (const float*)nullptr,
                           (const float*)nullptr, 0.f, t16, stats1, N);
        // u16 = bf16(relu(bn1(t)) @ W2 + b2)   (BN fused, +stats2)
        hipLaunchKernelGGL((k_mmx<IN_BF16BN, true>), dim3(ntiles), dim3(256), 0, stream,
                           t16, Wt16 + (size_t)(1 + L + l) * EMB * EMB, b2 + (size_t)l * EMB,
                           stats1, g1 + (size_t)l * EMB, be1 + (size_t)l * EMB, invN,
                           b16a, stats2, N);
        // h = relu(bn2(u)) + h   (in-place hb16; last layer -> fp32 d_out)
        if (l == L - 1) {
            hipLaunchKernelGGL((k_bnres<true>), dim3(1024), dim3(256), 0, stream,
                               b16a, stats2, g_out + (size_t)l * EMB,
                               be_out + (size_t)l * EMB, hb16, (float*)d_out,
                               invN, N * 16);
        } else {
            hipLaunchKernelGGL((k_bnres<false>), dim3(1024), dim3(256), 0, stream,
                               b16a, stats2, g_out + (size_t)l * EMB,
                               be_out + (size_t)l * EMB, hb16, (float*)nullptr,
                               invN, N * 16);
        }
    }
}